// Round 15
// baseline (13152.440 us; speedup 1.0000x reference)
//
#include <hip/hip_runtime.h>
#include <cstdint>

// GptOssExpertsLinear: E=16, H=D=2880, T=2048.
// out[t,h] = sum_e rw[t,e] * ( act(x@Wg[e]+bg, x@Wu[e]+bu) @ Wd[e] + bd )
// R15 = R14 with gateup BK 64->32: LDS 128->64KB => 2 blocks/CU, restoring
// m114 cross-block overlap absent at 1 block/CU. Same 8-phase schedule
// (1 gload per half-tile, uniform vmcnt(5)); new 64B-row swizzle
// pc = c ^ ((pr>>1)&3). NKT2=90 even -> tail-parity stage required.
// down (split-K=8), tcvt, reduce unchanged from R14.

#define ALPHA 1.702f
#define LIMIT 7.0f

static constexpr int E = 16;
static constexpr int H = 2880;
static constexpr int D = 2880;
static constexpr int T = 2048;
static constexpr int NKT = 45;       // 64-k steps (down)
static constexpr int NKT2 = 90;      // 32-k steps (gateup)
static constexpr int NPR = 5888;     // paired gate|up rows (2*2944)
static constexpr int HP  = 3072;     // padded H for down N
static constexpr int NZ  = 8;        // down split-K partials

typedef float        f32x4  __attribute__((ext_vector_type(4)));
typedef short        bf16x8 __attribute__((ext_vector_type(8)));

#define MFMA_BF16(a,b,c) __builtin_amdgcn_mfma_f32_16x16x32_bf16((a),(b),(c),0,0,0)
#define SBAR()        __builtin_amdgcn_s_barrier()
#define SCHED_FENCE() __builtin_amdgcn_sched_barrier(0)
#define PRIO1()       __builtin_amdgcn_s_setprio(1)
#define PRIO0()       __builtin_amdgcn_s_setprio(0)
#define LGK0()        asm volatile("s_waitcnt lgkmcnt(0)" ::: "memory")
#define VMC5()        asm volatile("s_waitcnt vmcnt(5)" ::: "memory")
#define VMC6()        asm volatile("s_waitcnt vmcnt(6)" ::: "memory")

__device__ __forceinline__ unsigned short f2bf(float f){
  unsigned u = __builtin_bit_cast(unsigned, f);
  u += 0x7fffu + ((u >> 16) & 1u);
  return (unsigned short)(u >> 16);
}
__device__ __forceinline__ unsigned pack2(float a, float b){
  return (unsigned)f2bf(a) | ((unsigned)f2bf(b) << 16);
}

__device__ __forceinline__ void gload_lds16(const void* g, void* l){
  __builtin_amdgcn_global_load_lds((const __attribute__((address_space(1))) unsigned*)g,
                                   (__attribute__((address_space(3))) unsigned*)l,
                                   16, 0, 0);
}

// x fp32 -> bf16, 8 elems/thread
__global__ void cvt_kernel(const float* __restrict__ in, unsigned short* __restrict__ ob, int n8){
  int i = blockIdx.x * 256 + threadIdx.x;
  if (i < n8){
    float4 a = ((const float4*)in)[2*i];
    float4 b = ((const float4*)in)[2*i+1];
    uint4 o;
    o.x = pack2(a.x, a.y); o.y = pack2(a.z, a.w);
    o.z = pack2(b.x, b.y); o.w = pack2(b.z, b.w);
    ((uint4*)ob)[i] = o;
  }
}

// W fp32 -> bf16 transpose with row remap; zero-pad rows beyond D.
// mode 0: dst row = (c/32)*64 + c%32       (gate half of paired layout)
// mode 1: dst row = (c/32)*64 + c%32 + 32  (up half)
// mode 2: dst row = c                      (plain transpose, down weights)
__global__ __launch_bounds__(256) void tcvt_kernel(
    const float* __restrict__ src, unsigned short* __restrict__ dst,
    int mode, size_t expStride, size_t rowStride)
{
  __shared__ unsigned short tl[64*72];
  const int t = threadIdx.x;
  const float* s = src + (size_t)blockIdx.z * H * D;
  unsigned short* o = dst + (size_t)blockIdx.z * expStride;
  const int r0 = blockIdx.x * 64, c0 = blockIdx.y * 64;

  if (c0 < D){
    int rr = t >> 2;
    #pragma unroll
    for (int p = 0; p < 4; ++p){
      int cc = ((t & 3) + p*4) * 4;
      float4 v = *(const float4*)(s + (size_t)(r0 + rr)*D + c0 + cc);
      tl[(cc+0)*72 + rr] = f2bf(v.x);
      tl[(cc+1)*72 + rr] = f2bf(v.y);
      tl[(cc+2)*72 + rr] = f2bf(v.z);
      tl[(cc+3)*72 + rr] = f2bf(v.w);
    }
    __syncthreads();
    #pragma unroll
    for (int p = 0; p < 2; ++p){
      int task = p*256 + t;
      int cl = task >> 3, ch = task & 7;
      int c = c0 + cl;
      int rowp = (mode < 2) ? ((c >> 5)*64 + (c & 31) + mode*32) : c;
      bf16x8 v = *(const bf16x8*)&tl[cl*72 + ch*8];
      *(bf16x8*)(o + (size_t)rowp*rowStride + r0 + ch*8) = v;
    }
  } else {
    #pragma unroll
    for (int p = 0; p < 2; ++p){
      int task = p*256 + t;
      int cl = task >> 3, ch = task & 7;
      int c = c0 + cl;
      int rowp = (mode < 2) ? ((c >> 5)*64 + (c & 31) + mode*32) : c;
      bf16x8 z = (bf16x8){0,0,0,0,0,0,0,0};
      *(bf16x8*)(o + (size_t)rowp*rowStride + r0 + ch*8) = z;
    }
  }
}

// sum NZ split-K partials + rank-E bias term rw@bd -> out
__global__ void reduce_kernel(const float* __restrict__ p,
                              const float* __restrict__ rw,
                              const float* __restrict__ bd,
                              float* __restrict__ out, int n4){
  int i = blockIdx.x * 256 + threadIdx.x;
  if (i < n4){
    int t  = i / (H/4);
    int h4 = (i % (H/4)) * 4;
    f32x4 a = ((const f32x4*)p)[i];
    #pragma unroll
    for (int z = 1; z < NZ; ++z)
      a += ((const f32x4*)(p + (size_t)z * T * H))[i];
    #pragma unroll
    for (int e = 0; e < E; ++e){
      float r = rw[t*E + e];
      f32x4 b = *(const f32x4*)(bd + (size_t)e*H + h4);
      a += r * b;
    }
    ((f32x4*)out)[i] = a;
  }
}

// ---------------- gate+up fused GEMM + activation (8-phase 256x256, BK=32) -
// grid (8, 23, ec); 512 thr = 8 waves (2M x 4N); 64KB LDS => 2 blocks/CU.
__global__ __launch_bounds__(512, 4) void gateup_kernel(
    const unsigned short* __restrict__ xb,    // [T][H] bf16
    const unsigned short* __restrict__ wGU,   // [ec][5888][H] paired bf16
    const float* __restrict__ bg,
    const float* __restrict__ bu,
    const float* __restrict__ rw,             // [T][E]
    unsigned short* __restrict__ inter,       // [T][KD] bf16 (rw-scaled)
    int e0, int KD)
{
  __shared__ short As[2][256*32];   // 16KB/buf (quarter-interleaved rows, 64B rows)
  __shared__ short Bs[2][256*32];   // => 64KB total

  const int t = threadIdx.x, lane = t & 63, wv = t >> 6;
  const int wm = wv >> 2, wn = wv & 3;

  int nbx = gridDim.x, nby = gridDim.y;
  int lin = blockIdx.x + nbx*(blockIdx.y + nby*blockIdx.z);
  int per = (nbx*nby*gridDim.z) >> 3;
  int id2 = (lin & 7)*per + (lin >> 3);
  int bx = id2 % nbx; int rem = id2 / nbx;
  int by = rem % nby; int ez = rem / nby;

  const int trow0 = bx*256, ncol0 = by*256;
  const int e = e0 + ez;
  const unsigned short* wg = wGU + (size_t)ez * NPR * H;

  f32x4 acc[8][4];
  #pragma unroll
  for (int i = 0; i < 8; ++i)
    #pragma unroll
    for (int j = 0; j < 4; ++j) acc[i][j] = (f32x4){0.f,0.f,0.f,0.f};

  // one half-tile = 128 rows x 32k = 8KB = exactly 1 gload/thread.
  // source pre-swizzle: physical chunk ch of physical row pr holds source
  // chunk ch ^ ((pr>>1)&3); pr = h*128 + (t>>2) -> sch = (t&3)^((t>>3)&3).
  auto stageA = [&](int kt, int b, int h){
    int sch = (t & 3) ^ ((t >> 3) & 3);
    int ps = t >> 2;                               // physical row within half
    int lr = h*64 + (ps & 63) + ((ps >> 6) << 7);  // logical tile row
    gload_lds16(xb + (size_t)(trow0 + lr)*H + kt*32 + sch*8,
                &As[b][h*4096 + t*8]);
  };
  auto stageB = [&](int kt, int b, int h){
    int sch = (t & 3) ^ ((t >> 3) & 3);
    int ps = t >> 2;
    int lr = h*32 + ((ps >> 5) << 6) + (ps & 31);
    gload_lds16(wg + (size_t)(ncol0 + lr)*H + kt*32 + sch*8,
                &Bs[b][h*4096 + t*8]);
  };

  bf16x8 af[4], bLo[2], bHi[2];
  auto readAh = [&](int b, int qa){
    #pragma unroll
    for (int mi = 0; mi < 4; ++mi){
      int r = wm*128 + qa*64 + mi*16 + (lane & 15);
      int q = r >> 6, qs = ((q & 1) << 1) | (q >> 1);
      int pr = qs*64 + (r & 63);
      int pc = (lane >> 4) ^ ((pr >> 1) & 3);
      af[mi] = *(const bf16x8*)&As[b][pr*32 + pc*8];
    }
  };
  auto readBh = [&](bf16x8 (&bf)[2], int b, int hb){
    #pragma unroll
    for (int ni = 0; ni < 2; ++ni){
      int rB = wn*64 + hb*32 + ni*16 + (lane & 15);
      int pr = ((rB >> 5) & 1)*128 + (rB >> 6)*32 + (rB & 31);
      int pc = (lane >> 4) ^ ((pr >> 1) & 3);
      bf[ni] = *(const bf16x8*)&Bs[b][pr*32 + pc*8];
    }
  };
  auto mfmaQ = [&](bf16x8 (&bf)[2], int qa, int hb){
    #pragma unroll
    for (int ni = 0; ni < 2; ++ni)
      #pragma unroll
      for (int mi = 0; mi < 4; ++mi)
        acc[qa*4+mi][hb*2+ni] = MFMA_BF16(af[mi], bf[ni], acc[qa*4+mi][hb*2+ni]);
  };

  // prologue: 7 halves (A-hi(1) staged at first p1)
  stageA(0,0,0); stageB(0,0,0); stageB(0,0,1); stageA(0,0,1);
  stageA(1,1,0); stageB(1,1,0); stageB(1,1,1);
  VMC5();
  SBAR();

  for (int it = 0; it < (NKT2-1)/2; ++it){
    int kt = 2*it;
    int ktA = (kt+2 < NKT2) ? kt+2 : NKT2-1;
    int ktB = (kt+3 < NKT2) ? kt+3 : NKT2-1;
    // p1: Q1(kt) af_lo x bLo ; stage A-hi(kt+1)->b1
    readAh(0, 0); readBh(bLo, 0, 0);
    stageA(kt+1, 1, 1);
    SCHED_FENCE(); SBAR(); LGK0(); SCHED_FENCE();
    PRIO1(); mfmaQ(bLo, 0, 0); PRIO0();
    VMC5(); SBAR();
    // p2: Q2(kt) af_lo x bHi ; stage A-lo(kt+2)->b0
    readBh(bHi, 0, 1);
    stageA(ktA, 0, 0);
    SCHED_FENCE(); SBAR(); LGK0(); SCHED_FENCE();
    PRIO1(); mfmaQ(bHi, 0, 1); PRIO0();
    VMC5(); SBAR();
    // p3: Q3(kt) af_hi x bHi ; stage B-lo(kt+2)->b0
    readAh(0, 1);
    stageB(ktA, 0, 0);
    SCHED_FENCE(); SBAR(); LGK0(); SCHED_FENCE();
    PRIO1(); mfmaQ(bHi, 1, 1); PRIO0();
    VMC5(); SBAR();
    // p4: Q4(kt) af_hi x bLo ; stage B-hi(kt+2)->b0
    stageB(ktA, 0, 1);
    SCHED_FENCE(); SBAR(); SCHED_FENCE();
    PRIO1(); mfmaQ(bLo, 1, 0); PRIO0();
    VMC5(); SBAR();
    // p5: Q1(kt+1) ; stage A-hi(kt+2)->b0
    readAh(1, 0); readBh(bLo, 1, 0);
    stageA(ktA, 0, 1);
    SCHED_FENCE(); SBAR(); LGK0(); SCHED_FENCE();
    PRIO1(); mfmaQ(bLo, 0, 0); PRIO0();
    VMC5(); SBAR();
    // p6: Q2(kt+1) ; stage A-lo(kt+3)->b1
    readBh(bHi, 1, 1);
    stageA(ktB, 1, 0);
    SCHED_FENCE(); SBAR(); LGK0(); SCHED_FENCE();
    PRIO1(); mfmaQ(bHi, 0, 1); PRIO0();
    VMC5(); SBAR();
    // p7: Q3(kt+1) ; stage B-lo(kt+3)->b1
    readAh(1, 1);
    stageB(ktB, 1, 0);
    SCHED_FENCE(); SBAR(); LGK0(); SCHED_FENCE();
    PRIO1(); mfmaQ(bHi, 1, 1); PRIO0();
    VMC5(); SBAR();
    // p8: Q4(kt+1) ; stage B-hi(kt+3)->b1
    stageB(ktB, 1, 1);
    SCHED_FENCE(); SBAR(); SCHED_FENCE();
    PRIO1(); mfmaQ(bLo, 1, 0); PRIO0();
    VMC5(); SBAR();
  }

  // NKT2=90 even: last tile's A-hi never staged by the loop -> stage here.
  stageA(NKT2-1, 1, 1);
  asm volatile("s_waitcnt vmcnt(0)" ::: "memory");
  SBAR();
  // tail: tiles NKT2-2 (b0), NKT2-1 (b1)
  for (int jt = NKT2-2; jt < NKT2; ++jt){
    int b = jt & 1;
    readAh(b, 0); readBh(bLo, b, 0); readBh(bHi, b, 1);
    LGK0(); SCHED_FENCE();
    mfmaQ(bLo, 0, 0); mfmaQ(bHi, 0, 1);
    readAh(b, 1);
    LGK0(); SCHED_FENCE();
    mfmaQ(bHi, 1, 1); mfmaQ(bLo, 1, 0);
  }

  // epilogue: bias + clamp + glu, scaled by rw -> inter[t][ez*D + d]
  const float* bgp = bg + (size_t)e * D;
  const float* bup = bu + (size_t)e * D;
  unsigned short* ip = inter + (size_t)ez * D;
  const int dbase = (by*4 + wn) * 32;
  #pragma unroll
  for (int g = 0; g < 2; ++g){
    int d0 = dbase + g*16;
    if (d0 < D){
      int d = d0 + (lane & 15);
      float bgv = bgp[d], buv = bup[d];
      #pragma unroll
      for (int mi = 0; mi < 8; ++mi){
        #pragma unroll
        for (int r = 0; r < 4; ++r){
          int trw = trow0 + wm*128 + mi*16 + (lane >> 4)*4 + r;
          float gv = acc[mi][g][r] + bgv;
          float uv = acc[mi][g+2][r] + buv;
          gv = fminf(gv, LIMIT);
          uv = fminf(fmaxf(uv, -LIMIT), LIMIT);
          float glu = gv / (1.f + __expf(-ALPHA * gv));
          float rv = rw[trw*E + e];
          ip[(size_t)trw * KD + d] = f2bf(rv * (uv + 1.f) * glu);
        }
      }
    }
  }
}

// ---------------- down: single GEMM over concatenated K, split-K=8 ---------
// grid (8, 12, NZ); 512 thr = 8 waves; tile 256x256; BK=64 (R14 verbatim).
__global__ __launch_bounds__(512, 2) void down_kernel(
    const unsigned short* __restrict__ inter, // [T][KD] bf16 (rw-scaled)
    const unsigned short* __restrict__ wdA,   // [3072][KD] bf16 (pad rows 0)
    float* __restrict__ pout,                 // [NZ][T][H] fp32 partials
    int nk64, int KD, int accum)
{
  __shared__ short As[2][256*64];
  __shared__ short Bs[2][256*64];

  const int t = threadIdx.x, lane = t & 63, wv = t >> 6;
  const int wm = wv >> 2, wn = wv & 3;

  int nbx = gridDim.x, nby = gridDim.y;
  int lin = blockIdx.x + nbx*(blockIdx.y + nby*blockIdx.z);
  int per = (nbx*nby*gridDim.z) >> 3;
  int id2 = (lin & 7)*per + (lin >> 3);
  int bx = id2 % nbx; int rem = id2 / nbx;
  int by = rem % nby; int z  = rem / nby;

  const int trow0 = bx*256, ncol0 = by*256;
  const int ksteps = nk64 / NZ;
  const int kst = z * ksteps, kend = kst + ksteps;

  f32x4 acc[8][4];
  #pragma unroll
  for (int i = 0; i < 8; ++i)
    #pragma unroll
    for (int j = 0; j < 4; ++j) acc[i][j] = (f32x4){0.f,0.f,0.f,0.f};

  auto stageA = [&](int kt, int b, int h){
    #pragma unroll
    for (int r2 = 0; r2 < 2; ++r2){
      int task = r2*512 + t;
      int ps = task >> 3, ch = task & 7, sch = ch ^ (ps & 7);
      int lr = h*64 + (ps & 63) + ((ps >> 6) << 7);
      gload_lds16(inter + (size_t)(trow0 + lr)*KD + kt*64 + sch*8,
                  &As[b][h*8192 + task*8]);
    }
  };
  auto stageB = [&](int kt, int b, int h){
    #pragma unroll
    for (int r2 = 0; r2 < 2; ++r2){
      int task = r2*512 + t;
      int ps = task >> 3, ch = task & 7, sch = ch ^ (ps & 7);
      int lr = h*32 + ((ps >> 5) << 6) + (ps & 31);
      gload_lds16(wdA + (size_t)(ncol0 + lr)*KD + kt*64 + sch*8,
                  &Bs[b][h*8192 + task*8]);
    }
  };

  bf16x8 af[4][2], bLo[2][2], bHi[2][2];
  auto readAh = [&](int b, int qa){
    #pragma unroll
    for (int mi = 0; mi < 4; ++mi){
      int r = wm*128 + qa*64 + mi*16 + (lane & 15);
      int q = r >> 6, qs = ((q & 1) << 1) | (q >> 1);
      int pr = qs*64 + (r & 63);
      #pragma unroll
      for (int kk = 0; kk < 2; ++kk){
        int pc = (kk*4 + (lane >> 4)) ^ (pr & 7);
        af[mi][kk] = *(const bf16x8*)&As[b][pr*64 + pc*8];
      }
    }
  };
  auto readBh = [&](bf16x8 (&bf)[2][2], int b, int hb){
    #pragma unroll
    for (int ni = 0; ni < 2; ++ni){
      int rB = wn*64 + hb*32 + ni*16 + (lane & 15);
      int pr = ((rB >> 5) & 1)*128 + (rB >> 6)*32 + (rB & 31);
      #pragma unroll
      for (int kk = 0; kk < 2; ++kk){
        int pc = (kk*4 + (lane >> 4)) ^ (pr & 7);
        bf[ni][kk] = *(const bf16x8*)&Bs[b][pr*64 + pc*8];
      }
    }
  };
  auto mfmaQ = [&](bf16x8 (&bf)[2][2], int qa, int hb){
    #pragma unroll
    for (int kk = 0; kk < 2; ++kk)
      #pragma unroll
      for (int ni = 0; ni < 2; ++ni)
        #pragma unroll
        for (int mi = 0; mi < 4; ++mi)
          acc[qa*4+mi][hb*2+ni] = MFMA_BF16(af[mi][kk], bf[ni][kk], acc[qa*4+mi][hb*2+ni]);
  };

  stageA(kst,0,0); stageB(kst,0,0); stageB(kst,0,1); stageA(kst,0,1);
  stageA(kst+1,1,0); stageB(kst+1,1,0); stageB(kst+1,1,1);
  asm volatile("s_waitcnt vmcnt(8)" ::: "memory");
  SBAR();

  const int nit = (ksteps - 1) >> 1;
  for (int it = 0; it < nit; ++it){
    int kt = kst + 2*it;
    int ktA = (kt+2 < kend) ? kt+2 : kend-1;
    int ktB = (kt+3 < kend) ? kt+3 : kend-1;
    readAh(0, 0); readBh(bLo, 0, 0);
    stageA(kt+1, 1, 1);
    SCHED_FENCE(); SBAR(); LGK0(); SCHED_FENCE();
    PRIO1(); mfmaQ(bLo, 0, 0); PRIO0();
    VMC6(); SBAR();
    readBh(bHi, 0, 1);
    stageA(ktA, 0, 0);
    SCHED_FENCE(); SBAR(); LGK0(); SCHED_FENCE();
    PRIO1(); mfmaQ(bHi, 0, 1); PRIO0();
    VMC6(); SBAR();
    readAh(0, 1);
    stageB(ktA, 0, 0);
    SCHED_FENCE(); SBAR(); LGK0(); SCHED_FENCE();
    PRIO1(); mfmaQ(bHi, 1, 1); PRIO0();
    VMC6(); SBAR();
    stageB(ktA, 0, 1);
    SCHED_FENCE(); SBAR(); SCHED_FENCE();
    PRIO1(); mfmaQ(bLo, 1, 0); PRIO0();
    VMC6(); SBAR();
    readAh(1, 0); readBh(bLo, 1, 0);
    stageA(ktA, 0, 1);
    SCHED_FENCE(); SBAR(); LGK0(); SCHED_FENCE();
    PRIO1(); mfmaQ(bLo, 0, 0); PRIO0();
    VMC6(); SBAR();
    readBh(bHi, 1, 1);
    stageA(ktB, 1, 0);
    SCHED_FENCE(); SBAR(); LGK0(); SCHED_FENCE();
    PRIO1(); mfmaQ(bHi, 0, 1); PRIO0();
    VMC6(); SBAR();
    readAh(1, 1);
    stageB(ktB, 1, 0);
    SCHED_FENCE(); SBAR(); LGK0(); SCHED_FENCE();
    PRIO1(); mfmaQ(bHi, 1, 1); PRIO0();
    VMC6(); SBAR();
    stageB(ktB, 1, 1);
    SCHED_FENCE(); SBAR(); SCHED_FENCE();
    PRIO1(); mfmaQ(bLo, 1, 0); PRIO0();
    VMC6(); SBAR();
  }

  // tail-parity fix (even ksteps): last tile's A-hi staged here
  if ((ksteps & 1) == 0)
    stageA(kend-1, 1, 1);

  asm volatile("s_waitcnt vmcnt(0)" ::: "memory");
  SBAR();
  for (int jt = 2*nit; jt < ksteps; ++jt){
    int b = jt & 1;
    readAh(b, 0); readBh(bLo, b, 0); readBh(bHi, b, 1);
    LGK0(); SCHED_FENCE();
    mfmaQ(bLo, 0, 0); mfmaQ(bHi, 0, 1);
    readAh(b, 1);
    LGK0(); SCHED_FENCE();
    mfmaQ(bHi, 1, 1); mfmaQ(bLo, 1, 0);
  }

  float* pp = pout + (size_t)z * T * H;
  #pragma unroll
  for (int j = 0; j < 4; ++j){
    int h0 = ncol0 + wn*64 + j*16;
    if (h0 < H){
      int h = h0 + (lane & 15);
      #pragma unroll
      for (int mi = 0; mi < 8; ++mi){
        #pragma unroll
        for (int r = 0; r < 4; ++r){
          int trw = trow0 + wm*128 + mi*16 + (lane >> 4)*4 + r;
          size_t oi = (size_t)trw * H + h;
          float v = acc[mi][j][r];
          if (accum) v += pp[oi];
          pp[oi] = v;
        }
      }
    }
  }
}

extern "C" void kernel_launch(void* const* d_in, const int* in_sizes, int n_in,
                              void* d_out, int out_size, void* d_ws, size_t ws_size,
                              hipStream_t stream) {
  const float* hs  = (const float*)d_in[0];
  const float* rwt = (const float*)d_in[1];
  const float* Wg  = (const float*)d_in[2];
  const float* bg  = (const float*)d_in[3];
  const float* Wu  = (const float*)d_in[4];
  const float* bu  = (const float*)d_in[5];
  const float* Wd  = (const float*)d_in[6];
  const float* bd  = (const float*)d_in[7];
  float* out = (float*)d_out;

  const size_t xbytes = (size_t)T * H * 2;            // 11.8 MB
  const size_t poutB  = (size_t)NZ * T * H * 4;       // 188.7 MB
  const size_t perE = (size_t)T*D*2 + (size_t)NPR*H*2 + (size_t)HP*D*2; // 63.4 MB

  long long avail = (long long)ws_size - (long long)(xbytes + poutB);
  int EC = (int)(avail / (long long)perE);
  if (EC > E) EC = E;
  EC -= EC % 8;                                        // ksteps divisibility
  if (EC < 8) EC = 8;
  const int KD = EC * D;

  unsigned short* xb    = (unsigned short*)d_ws;
  float*          pout  = (float*)((char*)d_ws + xbytes);
  unsigned short* inter = (unsigned short*)((char*)d_ws + xbytes + poutB);
  unsigned short* wGU   = inter + (size_t)T * KD;
  unsigned short* wdA   = wGU + (size_t)EC * NPR * H;

  cvt_kernel<<<(T*H/8 + 255)/256, 256, 0, stream>>>(hs, xb, T*H/8);

  for (int e0 = 0; e0 < E; e0 += EC){
    int ec = (E - e0 < EC) ? (E - e0) : EC;            // == EC (E=16, EC in {8,16})
    tcvt_kernel<<<dim3(45,46,ec), 256, 0, stream>>>(
        Wg + (size_t)e0*H*D, wGU, 0, (size_t)NPR*H, (size_t)H);
    tcvt_kernel<<<dim3(45,46,ec), 256, 0, stream>>>(
        Wu + (size_t)e0*H*D, wGU, 1, (size_t)NPR*H, (size_t)H);
    tcvt_kernel<<<dim3(45,48,ec), 256, 0, stream>>>(
        Wd + (size_t)e0*H*D, wdA, 2, (size_t)D, (size_t)KD);
    gateup_kernel<<<dim3(8, 23, ec), 512, 0, stream>>>(
        xb, wGU, bg, bu, rwt, inter, e0, KD);
    down_kernel<<<dim3(8, 12, NZ), 512, 0, stream>>>(
        inter, wdA, pout, ec*NKT, KD, e0 != 0);
  }
  reduce_kernel<<<(T*H/4 + 255)/256, 256, 0, stream>>>(pout, rwt, bd, out, T*H/4);
}

// Round 16
// 2006.080 us; speedup vs baseline: 6.5563x; 6.5563x over previous
//
#include <hip/hip_runtime.h>
#include <cstdint>

// GptOssExpertsLinear: E=16, H=D=2880, T=2048.
// out[t,h] = sum_e rw[t,e] * ( act(x@Wg[e]+bg, x@Wu[e]+bu) @ Wd[e] + bd )
// R16 = R14 verbatim (proven 2010us best). R15's BK=32 2-blocks/CU attempt
// spilled (acc[8][4]=128 VGPR > 128-cap at 4 waves/SIMD) -> 60GB scratch
// traffic. 256^2 tile cannot occupy 2 blocks/CU; reverted per decision rule.
// Structure: rw folded into gateup -> down is ONE GEMM over concatenated
// K = EC*2880, split-K=8 (768 blocks = 3 full CU rounds), 8-phase 256x256
// template with tail-parity fix. Bias via rank-16 rw@bd in reduce.

#define ALPHA 1.702f
#define LIMIT 7.0f

static constexpr int E = 16;
static constexpr int H = 2880;
static constexpr int D = 2880;
static constexpr int T = 2048;
static constexpr int NKT = 45;       // gateup K-steps of 64 (K=2880)
static constexpr int NPR = 5888;     // paired gate|up rows (2*2944)
static constexpr int HP  = 3072;     // padded H for down N
static constexpr int NZ  = 8;        // down split-K partials (768 blocks = 3 rounds)

typedef float        f32x4  __attribute__((ext_vector_type(4)));
typedef short        bf16x8 __attribute__((ext_vector_type(8)));

#define MFMA_BF16(a,b,c) __builtin_amdgcn_mfma_f32_16x16x32_bf16((a),(b),(c),0,0,0)
#define SBAR()        __builtin_amdgcn_s_barrier()
#define SCHED_FENCE() __builtin_amdgcn_sched_barrier(0)
#define PRIO1()       __builtin_amdgcn_s_setprio(1)
#define PRIO0()       __builtin_amdgcn_s_setprio(0)
#define LGK0()        asm volatile("s_waitcnt lgkmcnt(0)" ::: "memory")
#define VMC6()        asm volatile("s_waitcnt vmcnt(6)" ::: "memory")

__device__ __forceinline__ unsigned short f2bf(float f){
  unsigned u = __builtin_bit_cast(unsigned, f);
  u += 0x7fffu + ((u >> 16) & 1u);
  return (unsigned short)(u >> 16);
}
__device__ __forceinline__ unsigned pack2(float a, float b){
  return (unsigned)f2bf(a) | ((unsigned)f2bf(b) << 16);
}

__device__ __forceinline__ void gload_lds16(const void* g, void* l){
  __builtin_amdgcn_global_load_lds((const __attribute__((address_space(1))) unsigned*)g,
                                   (__attribute__((address_space(3))) unsigned*)l,
                                   16, 0, 0);
}

// x fp32 -> bf16, 8 elems/thread
__global__ void cvt_kernel(const float* __restrict__ in, unsigned short* __restrict__ ob, int n8){
  int i = blockIdx.x * 256 + threadIdx.x;
  if (i < n8){
    float4 a = ((const float4*)in)[2*i];
    float4 b = ((const float4*)in)[2*i+1];
    uint4 o;
    o.x = pack2(a.x, a.y); o.y = pack2(a.z, a.w);
    o.z = pack2(b.x, b.y); o.w = pack2(b.z, b.w);
    ((uint4*)ob)[i] = o;
  }
}

// W fp32 -> bf16 transpose with row remap; zero-pad rows beyond D.
// mode 0: dst row = (c/32)*64 + c%32       (gate half of paired layout)
// mode 1: dst row = (c/32)*64 + c%32 + 32  (up half)
// mode 2: dst row = c                      (plain transpose, down weights)
// dst element = dst + z*expStride + rowp*rowStride + k
__global__ __launch_bounds__(256) void tcvt_kernel(
    const float* __restrict__ src, unsigned short* __restrict__ dst,
    int mode, size_t expStride, size_t rowStride)
{
  __shared__ unsigned short tl[64*72];
  const int t = threadIdx.x;
  const float* s = src + (size_t)blockIdx.z * H * D;
  unsigned short* o = dst + (size_t)blockIdx.z * expStride;
  const int r0 = blockIdx.x * 64, c0 = blockIdx.y * 64;

  if (c0 < D){
    int rr = t >> 2;
    #pragma unroll
    for (int p = 0; p < 4; ++p){
      int cc = ((t & 3) + p*4) * 4;
      float4 v = *(const float4*)(s + (size_t)(r0 + rr)*D + c0 + cc);
      tl[(cc+0)*72 + rr] = f2bf(v.x);
      tl[(cc+1)*72 + rr] = f2bf(v.y);
      tl[(cc+2)*72 + rr] = f2bf(v.z);
      tl[(cc+3)*72 + rr] = f2bf(v.w);
    }
    __syncthreads();
    #pragma unroll
    for (int p = 0; p < 2; ++p){
      int task = p*256 + t;
      int cl = task >> 3, ch = task & 7;
      int c = c0 + cl;
      int rowp = (mode < 2) ? ((c >> 5)*64 + (c & 31) + mode*32) : c;
      bf16x8 v = *(const bf16x8*)&tl[cl*72 + ch*8];
      *(bf16x8*)(o + (size_t)rowp*rowStride + r0 + ch*8) = v;
    }
  } else {
    #pragma unroll
    for (int p = 0; p < 2; ++p){
      int task = p*256 + t;
      int cl = task >> 3, ch = task & 7;
      int c = c0 + cl;
      int rowp = (mode < 2) ? ((c >> 5)*64 + (c & 31) + mode*32) : c;
      bf16x8 z = (bf16x8){0,0,0,0,0,0,0,0};
      *(bf16x8*)(o + (size_t)rowp*rowStride + r0 + ch*8) = z;
    }
  }
}

// sum NZ split-K partials + rank-E bias term rw@bd -> out
__global__ void reduce_kernel(const float* __restrict__ p,
                              const float* __restrict__ rw,
                              const float* __restrict__ bd,
                              float* __restrict__ out, int n4){
  int i = blockIdx.x * 256 + threadIdx.x;
  if (i < n4){
    int t  = i / (H/4);
    int h4 = (i % (H/4)) * 4;
    f32x4 a = ((const f32x4*)p)[i];
    #pragma unroll
    for (int z = 1; z < NZ; ++z)
      a += ((const f32x4*)(p + (size_t)z * T * H))[i];
    #pragma unroll
    for (int e = 0; e < E; ++e){
      float r = rw[t*E + e];
      f32x4 b = *(const f32x4*)(bd + (size_t)e*H + h4);
      a += r * b;
    }
    ((f32x4*)out)[i] = a;
  }
}

// ---------------- gate+up fused GEMM + activation (8-phase 256x256) --------
// grid (8, 23, ec); 512 thr = 8 waves (2M x 4N); wave tile 128x64 paired.
__global__ __launch_bounds__(512, 2) void gateup_kernel(
    const unsigned short* __restrict__ xb,    // [T][H] bf16
    const unsigned short* __restrict__ wGU,   // [ec][5888][H] paired bf16
    const float* __restrict__ bg,
    const float* __restrict__ bu,
    const float* __restrict__ rw,             // [T][E]
    unsigned short* __restrict__ inter,       // [T][KD] bf16 (rw-scaled)
    int e0, int KD)
{
  __shared__ short As[2][256*64];   // 64KB (quarter-interleaved rows)
  __shared__ short Bs[2][256*64];   // 64KB => 128KB total

  const int t = threadIdx.x, lane = t & 63, wv = t >> 6;
  const int wm = wv >> 2, wn = wv & 3;

  int nbx = gridDim.x, nby = gridDim.y;
  int lin = blockIdx.x + nbx*(blockIdx.y + nby*blockIdx.z);
  int per = (nbx*nby*gridDim.z) >> 3;
  int id2 = (lin & 7)*per + (lin >> 3);
  int bx = id2 % nbx; int rem = id2 / nbx;
  int by = rem % nby; int ez = rem / nby;

  const int trow0 = bx*256, ncol0 = by*256;
  const int e = e0 + ez;
  const unsigned short* wg = wGU + (size_t)ez * NPR * H;

  f32x4 acc[8][4];
  #pragma unroll
  for (int i = 0; i < 8; ++i)
    #pragma unroll
    for (int j = 0; j < 4; ++j) acc[i][j] = (f32x4){0.f,0.f,0.f,0.f};

  auto stageA = [&](int kt, int b, int h){
    #pragma unroll
    for (int r2 = 0; r2 < 2; ++r2){
      int task = r2*512 + t;
      int ps = task >> 3, ch = task & 7, sch = ch ^ (ps & 7);
      int lr = h*64 + (ps & 63) + ((ps >> 6) << 7);
      gload_lds16(xb + (size_t)(trow0 + lr)*H + kt*64 + sch*8,
                  &As[b][h*8192 + task*8]);
    }
  };
  auto stageB = [&](int kt, int b, int h){
    #pragma unroll
    for (int r2 = 0; r2 < 2; ++r2){
      int task = r2*512 + t;
      int ps = task >> 3, ch = task & 7, sch = ch ^ (ps & 7);
      int lr = h*32 + ((ps >> 5) << 6) + (ps & 31);
      gload_lds16(wg + (size_t)(ncol0 + lr)*H + kt*64 + sch*8,
                  &Bs[b][h*8192 + task*8]);
    }
  };

  bf16x8 af[4][2], bLo[2][2], bHi[2][2];
  auto readAh = [&](int b, int qa){
    #pragma unroll
    for (int mi = 0; mi < 4; ++mi){
      int r = wm*128 + qa*64 + mi*16 + (lane & 15);
      int q = r >> 6, qs = ((q & 1) << 1) | (q >> 1);
      int pr = qs*64 + (r & 63);
      #pragma unroll
      for (int kk = 0; kk < 2; ++kk){
        int pc = (kk*4 + (lane >> 4)) ^ (pr & 7);
        af[mi][kk] = *(const bf16x8*)&As[b][pr*64 + pc*8];
      }
    }
  };
  auto readBh = [&](bf16x8 (&bf)[2][2], int b, int hb){
    #pragma unroll
    for (int ni = 0; ni < 2; ++ni){
      int rB = wn*64 + hb*32 + ni*16 + (lane & 15);
      int pr = ((rB >> 5) & 1)*128 + (rB >> 6)*32 + (rB & 31);
      #pragma unroll
      for (int kk = 0; kk < 2; ++kk){
        int pc = (kk*4 + (lane >> 4)) ^ (pr & 7);
        bf[ni][kk] = *(const bf16x8*)&Bs[b][pr*64 + pc*8];
      }
    }
  };
  auto mfmaQ = [&](bf16x8 (&bf)[2][2], int qa, int hb){
    #pragma unroll
    for (int kk = 0; kk < 2; ++kk)
      #pragma unroll
      for (int ni = 0; ni < 2; ++ni)
        #pragma unroll
        for (int mi = 0; mi < 4; ++mi)
          acc[qa*4+mi][hb*2+ni] = MFMA_BF16(af[mi][kk], bf[ni][kk], acc[qa*4+mi][hb*2+ni]);
  };

  stageA(0,0,0); stageB(0,0,0); stageB(0,0,1); stageA(0,0,1);
  stageA(1,1,0); stageB(1,1,0); stageB(1,1,1);
  asm volatile("s_waitcnt vmcnt(8)" ::: "memory");
  SBAR();

  for (int it = 0; it < 22; ++it){
    int kt = 2*it;
    int ktA = (kt+2 < NKT) ? kt+2 : NKT-1;
    int ktB = (kt+3 < NKT) ? kt+3 : NKT-1;
    readAh(0, 0); readBh(bLo, 0, 0);
    stageA(kt+1, 1, 1);
    SCHED_FENCE(); SBAR(); LGK0(); SCHED_FENCE();
    PRIO1(); mfmaQ(bLo, 0, 0); PRIO0();
    VMC6(); SBAR();
    readBh(bHi, 0, 1);
    stageA(ktA, 0, 0);
    SCHED_FENCE(); SBAR(); LGK0(); SCHED_FENCE();
    PRIO1(); mfmaQ(bHi, 0, 1); PRIO0();
    VMC6(); SBAR();
    readAh(0, 1);
    stageB(ktA, 0, 0);
    SCHED_FENCE(); SBAR(); LGK0(); SCHED_FENCE();
    PRIO1(); mfmaQ(bHi, 1, 1); PRIO0();
    VMC6(); SBAR();
    stageB(ktA, 0, 1);
    SCHED_FENCE(); SBAR(); SCHED_FENCE();
    PRIO1(); mfmaQ(bLo, 1, 0); PRIO0();
    VMC6(); SBAR();
    readAh(1, 0); readBh(bLo, 1, 0);
    stageA(ktA, 0, 1);
    SCHED_FENCE(); SBAR(); LGK0(); SCHED_FENCE();
    PRIO1(); mfmaQ(bLo, 0, 0); PRIO0();
    VMC6(); SBAR();
    readBh(bHi, 1, 1);
    stageA(ktB, 1, 0);
    SCHED_FENCE(); SBAR(); LGK0(); SCHED_FENCE();
    PRIO1(); mfmaQ(bHi, 0, 1); PRIO0();
    VMC6(); SBAR();
    readAh(1, 1);
    stageB(ktB, 1, 0);
    SCHED_FENCE(); SBAR(); LGK0(); SCHED_FENCE();
    PRIO1(); mfmaQ(bHi, 1, 1); PRIO0();
    VMC6(); SBAR();
    stageB(ktB, 1, 1);
    SCHED_FENCE(); SBAR(); SCHED_FENCE();
    PRIO1(); mfmaQ(bLo, 1, 0); PRIO0();
    VMC6(); SBAR();
  }

  asm volatile("s_waitcnt vmcnt(0)" ::: "memory");
  SBAR();
  readAh(0, 0); readBh(bLo, 0, 0); readBh(bHi, 0, 1);
  LGK0(); SCHED_FENCE();
  mfmaQ(bLo, 0, 0); mfmaQ(bHi, 0, 1);
  readAh(0, 1);
  LGK0(); SCHED_FENCE();
  mfmaQ(bHi, 1, 1); mfmaQ(bLo, 1, 0);

  // epilogue: bias + clamp + glu, scaled by rw -> inter[t][ez*D + d]
  const float* bgp = bg + (size_t)e * D;
  const float* bup = bu + (size_t)e * D;
  unsigned short* ip = inter + (size_t)ez * D;
  const int dbase = (by*4 + wn) * 32;
  #pragma unroll
  for (int g = 0; g < 2; ++g){
    int d0 = dbase + g*16;
    if (d0 < D){
      int d = d0 + (lane & 15);
      float bgv = bgp[d], buv = bup[d];
      #pragma unroll
      for (int mi = 0; mi < 8; ++mi){
        #pragma unroll
        for (int r = 0; r < 4; ++r){
          int trw = trow0 + wm*128 + mi*16 + (lane >> 4)*4 + r;
          float gv = acc[mi][g][r] + bgv;
          float uv = acc[mi][g+2][r] + buv;
          gv = fminf(gv, LIMIT);
          uv = fminf(fmaxf(uv, -LIMIT), LIMIT);
          float glu = gv / (1.f + __expf(-ALPHA * gv));
          float rv = rw[trw*E + e];
          ip[(size_t)trw * KD + d] = f2bf(rv * (uv + 1.f) * glu);
        }
      }
    }
  }
}

// ---------------- down: single GEMM over concatenated K, split-K=8 ---------
// grid (8, 12, NZ); 512 thr = 8 waves; tile 256x256; generic trip count.
__global__ __launch_bounds__(512, 2) void down_kernel(
    const unsigned short* __restrict__ inter, // [T][KD] bf16 (rw-scaled)
    const unsigned short* __restrict__ wdA,   // [3072][KD] bf16 (pad rows 0)
    float* __restrict__ pout,                 // [NZ][T][H] fp32 partials
    int nk64, int KD, int accum)
{
  __shared__ short As[2][256*64];
  __shared__ short Bs[2][256*64];

  const int t = threadIdx.x, lane = t & 63, wv = t >> 6;
  const int wm = wv >> 2, wn = wv & 3;

  int nbx = gridDim.x, nby = gridDim.y;
  int lin = blockIdx.x + nbx*(blockIdx.y + nby*blockIdx.z);
  int per = (nbx*nby*gridDim.z) >> 3;
  int id2 = (lin & 7)*per + (lin >> 3);
  int bx = id2 % nbx; int rem = id2 / nbx;
  int by = rem % nby; int z  = rem / nby;

  const int trow0 = bx*256, ncol0 = by*256;
  const int ksteps = nk64 / NZ;           // per split-K slice
  const int kst = z * ksteps, kend = kst + ksteps;

  f32x4 acc[8][4];
  #pragma unroll
  for (int i = 0; i < 8; ++i)
    #pragma unroll
    for (int j = 0; j < 4; ++j) acc[i][j] = (f32x4){0.f,0.f,0.f,0.f};

  auto stageA = [&](int kt, int b, int h){
    #pragma unroll
    for (int r2 = 0; r2 < 2; ++r2){
      int task = r2*512 + t;
      int ps = task >> 3, ch = task & 7, sch = ch ^ (ps & 7);
      int lr = h*64 + (ps & 63) + ((ps >> 6) << 7);
      gload_lds16(inter + (size_t)(trow0 + lr)*KD + kt*64 + sch*8,
                  &As[b][h*8192 + task*8]);
    }
  };
  auto stageB = [&](int kt, int b, int h){
    #pragma unroll
    for (int r2 = 0; r2 < 2; ++r2){
      int task = r2*512 + t;
      int ps = task >> 3, ch = task & 7, sch = ch ^ (ps & 7);
      int lr = h*32 + ((ps >> 5) << 6) + (ps & 31);
      gload_lds16(wdA + (size_t)(ncol0 + lr)*KD + kt*64 + sch*8,
                  &Bs[b][h*8192 + task*8]);
    }
  };

  bf16x8 af[4][2], bLo[2][2], bHi[2][2];
  auto readAh = [&](int b, int qa){
    #pragma unroll
    for (int mi = 0; mi < 4; ++mi){
      int r = wm*128 + qa*64 + mi*16 + (lane & 15);
      int q = r >> 6, qs = ((q & 1) << 1) | (q >> 1);
      int pr = qs*64 + (r & 63);
      #pragma unroll
      for (int kk = 0; kk < 2; ++kk){
        int pc = (kk*4 + (lane >> 4)) ^ (pr & 7);
        af[mi][kk] = *(const bf16x8*)&As[b][pr*64 + pc*8];
      }
    }
  };
  auto readBh = [&](bf16x8 (&bf)[2][2], int b, int hb){
    #pragma unroll
    for (int ni = 0; ni < 2; ++ni){
      int rB = wn*64 + hb*32 + ni*16 + (lane & 15);
      int pr = ((rB >> 5) & 1)*128 + (rB >> 6)*32 + (rB & 31);
      #pragma unroll
      for (int kk = 0; kk < 2; ++kk){
        int pc = (kk*4 + (lane >> 4)) ^ (pr & 7);
        bf[ni][kk] = *(const bf16x8*)&Bs[b][pr*64 + pc*8];
      }
    }
  };
  auto mfmaQ = [&](bf16x8 (&bf)[2][2], int qa, int hb){
    #pragma unroll
    for (int kk = 0; kk < 2; ++kk)
      #pragma unroll
      for (int ni = 0; ni < 2; ++ni)
        #pragma unroll
        for (int mi = 0; mi < 4; ++mi)
          acc[qa*4+mi][hb*2+ni] = MFMA_BF16(af[mi][kk], bf[ni][kk], acc[qa*4+mi][hb*2+ni]);
  };

  stageA(kst,0,0); stageB(kst,0,0); stageB(kst,0,1); stageA(kst,0,1);
  stageA(kst+1,1,0); stageB(kst+1,1,0); stageB(kst+1,1,1);
  asm volatile("s_waitcnt vmcnt(8)" ::: "memory");
  SBAR();

  const int nit = (ksteps - 1) >> 1;      // full 2-tile iterations
  for (int it = 0; it < nit; ++it){
    int kt = kst + 2*it;
    int ktA = (kt+2 < kend) ? kt+2 : kend-1;
    int ktB = (kt+3 < kend) ? kt+3 : kend-1;
    readAh(0, 0); readBh(bLo, 0, 0);
    stageA(kt+1, 1, 1);
    SCHED_FENCE(); SBAR(); LGK0(); SCHED_FENCE();
    PRIO1(); mfmaQ(bLo, 0, 0); PRIO0();
    VMC6(); SBAR();
    readBh(bHi, 0, 1);
    stageA(ktA, 0, 0);
    SCHED_FENCE(); SBAR(); LGK0(); SCHED_FENCE();
    PRIO1(); mfmaQ(bHi, 0, 1); PRIO0();
    VMC6(); SBAR();
    readAh(0, 1);
    stageB(ktA, 0, 0);
    SCHED_FENCE(); SBAR(); LGK0(); SCHED_FENCE();
    PRIO1(); mfmaQ(bHi, 1, 1); PRIO0();
    VMC6(); SBAR();
    stageB(ktA, 0, 1);
    SCHED_FENCE(); SBAR(); SCHED_FENCE();
    PRIO1(); mfmaQ(bLo, 1, 0); PRIO0();
    VMC6(); SBAR();
    readAh(1, 0); readBh(bLo, 1, 0);
    stageA(ktA, 0, 1);
    SCHED_FENCE(); SBAR(); LGK0(); SCHED_FENCE();
    PRIO1(); mfmaQ(bLo, 0, 0); PRIO0();
    VMC6(); SBAR();
    readBh(bHi, 1, 1);
    stageA(ktB, 1, 0);
    SCHED_FENCE(); SBAR(); LGK0(); SCHED_FENCE();
    PRIO1(); mfmaQ(bHi, 0, 1); PRIO0();
    VMC6(); SBAR();
    readAh(1, 1);
    stageB(ktB, 1, 0);
    SCHED_FENCE(); SBAR(); LGK0(); SCHED_FENCE();
    PRIO1(); mfmaQ(bHi, 1, 1); PRIO0();
    VMC6(); SBAR();
    stageB(ktB, 1, 1);
    SCHED_FENCE(); SBAR(); SCHED_FENCE();
    PRIO1(); mfmaQ(bLo, 1, 0); PRIO0();
    VMC6(); SBAR();
  }

  // TAIL-PARITY FIX: for EVEN ksteps the last tile's A-hi half is staged by
  // the (nonexistent) next iteration's p1 -> stage it here. Safe: all reads
  // of that region finished before the loop's final barrier, and the tail
  // reads only after vmcnt(0)+barrier below.
  if ((ksteps & 1) == 0)
    stageA(kend-1, 1, 1);

  asm volatile("s_waitcnt vmcnt(0)" ::: "memory");
  SBAR();
  for (int jt = 2*nit; jt < ksteps; ++jt){
    int b = jt & 1;
    readAh(b, 0); readBh(bLo, b, 0); readBh(bHi, b, 1);
    LGK0(); SCHED_FENCE();
    mfmaQ(bLo, 0, 0); mfmaQ(bHi, 0, 1);
    readAh(b, 1);
    LGK0(); SCHED_FENCE();
    mfmaQ(bHi, 1, 1); mfmaQ(bLo, 1, 0);
  }

  // epilogue: partial[z] = acc (accumulate across chunk passes)
  float* pp = pout + (size_t)z * T * H;
  #pragma unroll
  for (int j = 0; j < 4; ++j){
    int h0 = ncol0 + wn*64 + j*16;
    if (h0 < H){
      int h = h0 + (lane & 15);
      #pragma unroll
      for (int mi = 0; mi < 8; ++mi){
        #pragma unroll
        for (int r = 0; r < 4; ++r){
          int trw = trow0 + wm*128 + mi*16 + (lane >> 4)*4 + r;
          size_t oi = (size_t)trw * H + h;
          float v = acc[mi][j][r];
          if (accum) v += pp[oi];
          pp[oi] = v;
        }
      }
    }
  }
}

extern "C" void kernel_launch(void* const* d_in, const int* in_sizes, int n_in,
                              void* d_out, int out_size, void* d_ws, size_t ws_size,
                              hipStream_t stream) {
  const float* hs  = (const float*)d_in[0];
  const float* rwt = (const float*)d_in[1];
  const float* Wg  = (const float*)d_in[2];
  const float* bg  = (const float*)d_in[3];
  const float* Wu  = (const float*)d_in[4];
  const float* bu  = (const float*)d_in[5];
  const float* Wd  = (const float*)d_in[6];
  const float* bd  = (const float*)d_in[7];
  float* out = (float*)d_out;

  const size_t xbytes = (size_t)T * H * 2;            // 11.8 MB
  const size_t poutB  = (size_t)NZ * T * H * 4;       // 188.7 MB
  // per expert: inter column block + paired wGU + wdA column block
  const size_t perE = (size_t)T*D*2 + (size_t)NPR*H*2 + (size_t)HP*D*2; // 63.4 MB

  long long avail = (long long)ws_size - (long long)(xbytes + poutB);
  int EC = (int)(avail / (long long)perE);
  if (EC > E) EC = E;
  EC -= EC % 8;                                        // ksteps divisibility (NZ=8, 45 odd)
  if (EC < 8) EC = 8;
  const int KD = EC * D;

  unsigned short* xb    = (unsigned short*)d_ws;
  float*          pout  = (float*)((char*)d_ws + xbytes);
  unsigned short* inter = (unsigned short*)((char*)d_ws + xbytes + poutB);
  unsigned short* wGU   = inter + (size_t)T * KD;
  unsigned short* wdA   = wGU + (size_t)EC * NPR * H;

  cvt_kernel<<<(T*H/8 + 255)/256, 256, 0, stream>>>(hs, xb, T*H/8);

  for (int e0 = 0; e0 < E; e0 += EC){
    int ec = (E - e0 < EC) ? (E - e0) : EC;            // == EC (E=16, EC in {8,16})
    tcvt_kernel<<<dim3(45,46,ec), 256, 0, stream>>>(
        Wg + (size_t)e0*H*D, wGU, 0, (size_t)NPR*H, (size_t)H);
    tcvt_kernel<<<dim3(45,46,ec), 256, 0, stream>>>(
        Wu + (size_t)e0*H*D, wGU, 1, (size_t)NPR*H, (size_t)H);
    tcvt_kernel<<<dim3(45,48,ec), 256, 0, stream>>>(
        Wd + (size_t)e0*H*D, wdA, 2, (size_t)D, (size_t)KD);
    gateup_kernel<<<dim3(8, 23, ec), 512, 0, stream>>>(
        xb, wGU, bg, bu, rwt, inter, e0, KD);
    down_kernel<<<dim3(8, 12, NZ), 512, 0, stream>>>(
        inter, wdA, pout, ec*NKT, KD, e0 != 0);
  }
  reduce_kernel<<<(T*H/4 + 255)/256, 256, 0, stream>>>(pout, rwt, bd, out, T*H/4);
}